// Round 6
// baseline (227.040 us; speedup 1.0000x reference)
//
#include <hip/hip_runtime.h>
#include <hip/hip_bf16.h>

#define BB 64
#define SS 4096
#define EE 128   // EMB_DIM
#define DD 128   // DEC_DIM
#define FAN 256
#define TILES 8            // 64-row s-tiles per logits block
#define ROWS (TILES * 64)  // 512 s-rows per block

typedef __bf16 bf16x8 __attribute__((ext_vector_type(8)));
typedef unsigned short u16x8 __attribute__((ext_vector_type(8)));
typedef float f32x4 __attribute__((ext_vector_type(4)));

__device__ inline bf16x8 ld_frag(const unsigned short* p) {
    union { u16x8 u; bf16x8 b; } c;
    c.u = *(const u16x8*)p;
    return c.b;
}

__device__ inline uint2 f4_to_bf4(float4 f) {
    union { __hip_bfloat162 b; unsigned u; } lo, hi;
    lo.b = __float22bfloat162_rn(make_float2(f.x, f.y));
    hi.b = __float22bfloat162_rn(make_float2(f.z, f.w));
    return make_uint2(lo.u, hi.u);
}

__device__ inline float tanh_fast(float x) {
    float ax = fabsf(x);
    float e = __expf(-2.0f * ax);
    float t = (1.0f - e) * __builtin_amdgcn_rcpf(1.0f + e);
    return x < 0.0f ? -t : t;
}

// ---------------------------------------------------------------------------
// Kernel 1: h_proj (fp32), We -> bf16 row-major Wb (no swizzle needed now),
// v copy. grid 64 x 256.
// ---------------------------------------------------------------------------
__global__ __launch_bounds__(256) void prep_kernel(
        const float* __restrict__ hidden, const float* __restrict__ W_attn,
        const float* __restrict__ b_attn, const float* __restrict__ v_w,
        float* __restrict__ hproj, unsigned short* __restrict__ Wb,
        float* __restrict__ v_out) {
    const int b = blockIdx.x;
    const int t = threadIdx.x;
    if (t < 128) {
        float acc = b_attn[t];
        const float4* hrow = (const float4*)(hidden + b * DD);
        const float4* wrow = (const float4*)(W_attn + t * FAN);
        #pragma unroll
        for (int e = 0; e < 32; e++) {
            float4 h = hrow[e], w = wrow[e];
            acc += h.x * w.x + h.y * w.y + h.z * w.z + h.w * w.w;
        }
        hproj[b * DD + t] = acc;
        if (b == 0) v_out[t] = v_w[t];
    } else {
        int tt = t - 128;
        int d  = 2 * b + (tt >> 6);
        int e0 = (tt & 63) * 2;          // writes bf16 pair (e0, e0+1)
        float2 src = *(const float2*)(W_attn + d * FAN + DD + e0);
        union { __hip_bfloat162 bb; unsigned u; } c;
        c.bb = __float22bfloat162_rn(src);
        *(unsigned*)&Wb[d * EE + e0] = c.u;
    }
}

// ---------------------------------------------------------------------------
// Kernel 2: out[b][s] = exp(v . tanh(hproj[b] + X[s] @ We^T)) (0 if masked).
// NO LDS: each wave loads the full We (32 KB, L2-resident) into 128 VGPRs
// ONCE and feeds MFMA from registers for all 8 tiles. This removes the
// per-tile 32KB-per-wave LDS re-read (~10 us/CU of ds_read_b128 time, the
// dominant non-fixed cost), the staging DMA, and the only __syncthreads.
// __launch_bounds__(256,2): 2 waves/SIMD, 256-VGPR budget (audit ~235).
// grid (8, 64) x 256 = 512 blocks = 2 blocks/CU, all resident.
// ---------------------------------------------------------------------------
__global__ __launch_bounds__(256, 2) void logits_kernel(
        const float* __restrict__ seq_embs, const int* __restrict__ mask,
        const float* __restrict__ hproj, const unsigned short* __restrict__ Wb,
        const float* __restrict__ v, float* __restrict__ out,
        float* __restrict__ psums) {
    const int b    = blockIdx.y;
    const int g    = blockIdx.x;
    const int tid  = threadIdx.x;
    const int wave = tid >> 6;
    const int lane = tid & 63;
    const int m    = lane & 15;
    const int quad = lane >> 4;
    const int arow = wave * 16 + m;       // this lane's s-row within each tile

    // --- B-operand: all 32 We fragments -> 128 VGPRs. One-time, L2-hot.
    // Frag (kk,t): lanes read We[d = t*16+m][e = kk*32+quad*8 .. +7].
    bf16x8 bw[4][8];
    #pragma unroll
    for (int kk = 0; kk < 4; kk++)
        #pragma unroll
        for (int t = 0; t < 8; t++)
            bw[kk][t] = ld_frag(Wb + (t * 16 + m) * EE + kk * 32 + quad * 8);

    const int* __restrict__ mask_g = mask + (size_t)b * SS + g * ROWS;
    const float* __restrict__ xbase = seq_embs
        + (size_t)(g * ROWS + arow) * (BB * EE)
        + (size_t)b * EE + quad * 8;

    // --- Prefetch tile 0's mask + A-frags (overlaps the bw loads).
    int am[2];
    int4 mq[2];
    bf16x8 af[2][4];
    {
        am[0] = mask_g[arow];
        mq[0] = *(const int4*)(mask_g + wave * 16 + quad * 4);
        const float* xrow = xbase;
        #pragma unroll
        for (int kk = 0; kk < 4; kk++) {
            union { uint4 q; bf16x8 bf; } c;
            c.q = make_uint4(0u, 0u, 0u, 0u);
            if (am[0] != 0) {
                float4 f0 = *(const float4*)(xrow + kk * 32);
                float4 f1 = *(const float4*)(xrow + kk * 32 + 4);
                uint2 a = f4_to_bf4(f0), bq = f4_to_bf4(f1);
                c.q = make_uint4(a.x, a.y, bq.x, bq.y);
            }
            af[0][kk] = c.bf;
        }
    }

    // --- Per-lane epilogue constants (L2-hot).
    float hp_r[8], v_r[8];
    #pragma unroll
    for (int t = 0; t < 8; t++) {
        hp_r[t] = hproj[b * DD + t * 16 + m];
        v_r[t]  = v[t * 16 + m];
    }

    float blocksum = 0.0f;

    #pragma unroll
    for (int tile = 0; tile < TILES; tile++) {
        const int cur = tile & 1;
        // Prefetch next tile's mask + A-frags (independent of this tile's MFMA).
        if (tile + 1 < TILES) {
            const int nxt = cur ^ 1;
            am[nxt] = mask_g[(tile + 1) * 64 + arow];
            mq[nxt] = *(const int4*)(mask_g + (tile + 1) * 64 + wave * 16 + quad * 4);
            const float* xrow = xbase + (size_t)((tile + 1) * 64) * (BB * EE);
            #pragma unroll
            for (int kk = 0; kk < 4; kk++) {
                union { uint4 q; bf16x8 bf; } c;
                c.q = make_uint4(0u, 0u, 0u, 0u);
                if (am[nxt] != 0) {
                    float4 f0 = *(const float4*)(xrow + kk * 32);
                    float4 f1 = *(const float4*)(xrow + kk * 32 + 4);
                    uint2 a = f4_to_bf4(f0), bq = f4_to_bf4(f1);
                    c.q = make_uint4(a.x, a.y, bq.x, bq.y);
                }
                af[nxt][kk] = c.bf;
            }
        }

        // --- MFMA: 64 s-rows x 128 d, K=128; all operands in registers.
        // 8 independent acc chains (kk-outer / t-inner).
        f32x4 acc[8];
        #pragma unroll
        for (int t = 0; t < 8; t++) acc[t] = (f32x4){0.f, 0.f, 0.f, 0.f};
        #pragma unroll
        for (int kk = 0; kk < 4; kk++) {
            #pragma unroll
            for (int t = 0; t < 8; t++)
                acc[t] = __builtin_amdgcn_mfma_f32_16x16x32_bf16(af[cur][kk], bw[kk][t], acc[t], 0, 0, 0);
        }

        // --- Deferred epilogue: logit -> exp, mask-guarded.
        // Max-free exp safe: |logit| <= ||v||_1 <= 128/sqrt(128) = 11.31.
        const int mqa[4] = {mq[cur].x, mq[cur].y, mq[cur].z, mq[cur].w};
        float red[4];
        #pragma unroll
        for (int r = 0; r < 4; r++) {
            float red_r = 0.0f;
            if (mqa[r] != 0) {   // uniform across the 16-lane m-group: shfl-safe
                float part = 0.f;
                #pragma unroll
                for (int t = 0; t < 8; t++)
                    part += v_r[t] * tanh_fast(hp_r[t] + acc[t][r]);
                part += __shfl_xor(part, 1);
                part += __shfl_xor(part, 2);
                part += __shfl_xor(part, 4);
                part += __shfl_xor(part, 8);
                red_r = __expf(part);
            }
            red[r] = red_r;
            blocksum += red_r;
        }
        if (m == 0) {
            *(float4*)&out[(size_t)b * SS + g * ROWS + tile * 64
                           + wave * 16 + quad * 4] =
                make_float4(red[0], red[1], red[2], red[3]);
        }
    }

    // One plain store per wave (no atomics, no hot-line contention).
    blocksum += __shfl_xor(blocksum, 16);
    blocksum += __shfl_xor(blocksum, 32);
    if (lane == 0) psums[(b * 8 + g) * 4 + wave] = blocksum;
}

// ---------------------------------------------------------------------------
// Kernel 3: reduce the 32 per-wave partials of row b, then out[b][s] *= inv.
// grid (4, 64) x 256.
// ---------------------------------------------------------------------------
__global__ __launch_bounds__(256) void norm_kernel(
        float* __restrict__ out, const float* __restrict__ psums) {
    const int b = blockIdx.y;
    const int tid = threadIdx.x;
    float p = psums[b * 32 + (tid & 31)];    // 32 partials, L2-hot (dup-loaded)
    #pragma unroll
    for (int off = 16; off >= 1; off >>= 1)
        p += __shfl_xor(p, off);
    const float inv = 1.0f / p;              // all lanes hold the full row sum
    const int i = (blockIdx.x * 256 + tid) * 4;
    float4 v = *(float4*)&out[(size_t)b * SS + i];
    v.x *= inv; v.y *= inv; v.z *= inv; v.w *= inv;
    *(float4*)&out[(size_t)b * SS + i] = v;
}

extern "C" void kernel_launch(void* const* d_in, const int* in_sizes, int n_in,
                              void* d_out, int out_size, void* d_ws, size_t ws_size,
                              hipStream_t stream) {
    const float* hidden   = (const float*)d_in[0];
    const float* seq_embs = (const float*)d_in[1];
    const int*   mask     = (const int*)d_in[2];
    const float* W_attn   = (const float*)d_in[3];
    const float* b_attn   = (const float*)d_in[4];
    const float* v_w      = (const float*)d_in[5];
    float* out = (float*)d_out;

    float*          hproj = (float*)d_ws;                            // 32 KB
    unsigned short* Wb    = (unsigned short*)((char*)d_ws + 32768);  // 32 KB bf16 row-major
    float*          vv    = (float*)((char*)d_ws + 65536);           // 512 B
    float*          psums = (float*)((char*)d_ws + 66048);           // 8 KB (64 x 32)

    prep_kernel<<<64, 256, 0, stream>>>(hidden, W_attn, b_attn, v_w, hproj, Wb, vv);
    dim3 grid(SS / ROWS, BB);          // (8, 64)
    logits_kernel<<<grid, 256, 0, stream>>>(seq_embs, mask, hproj, Wb, vv, out, psums);
    dim3 ngrid(SS / (256 * 4), BB);    // (4, 64)
    norm_kernel<<<ngrid, 256, 0, stream>>>(out, psums);
}

// Round 7
// 215.016 us; speedup vs baseline: 1.0559x; 1.0559x over previous
//
#include <hip/hip_runtime.h>
#include <hip/hip_bf16.h>

#define BB 64
#define SS 4096
#define EE 128   // EMB_DIM
#define DD 128   // DEC_DIM
#define FAN 256
#define TILES 4            // 64-row s-tiles per logits block
#define ROWS (TILES * 64)  // 256 s-rows per block

typedef __bf16 bf16x8 __attribute__((ext_vector_type(8)));
typedef unsigned short u16x8 __attribute__((ext_vector_type(8)));
typedef float f32x4 __attribute__((ext_vector_type(4)));

__device__ inline bf16x8 ld_frag_lds(const unsigned char* p) {
    union { u16x8 u; bf16x8 b; } c;
    c.u = *(const u16x8*)p;
    return c.b;
}

__device__ inline uint2 f4_to_bf4(float4 f) {
    union { __hip_bfloat162 b; unsigned u; } lo, hi;
    lo.b = __float22bfloat162_rn(make_float2(f.x, f.y));
    hi.b = __float22bfloat162_rn(make_float2(f.z, f.w));
    return make_uint2(lo.u, hi.u);
}

__device__ inline float tanh_fast(float x) {
    float ax = fabsf(x);
    float e = __expf(-2.0f * ax);
    float t = (1.0f - e) * __builtin_amdgcn_rcpf(1.0f + e);
    return x < 0.0f ? -t : t;
}

// ---------------------------------------------------------------------------
// Kernel 1: h_proj (fp32), We -> bf16 PRE-SWIZZLED LDS image, v copy.
// Swizzle: byte offset for (d, ebyte) is d*256 + (ebyte ^ ((d&7)<<4)).
// grid 64 x 256
// ---------------------------------------------------------------------------
__global__ __launch_bounds__(256) void prep_kernel(
        const float* __restrict__ hidden, const float* __restrict__ W_attn,
        const float* __restrict__ b_attn, const float* __restrict__ v_w,
        float* __restrict__ hproj, unsigned char* __restrict__ Wb,
        float* __restrict__ v_out) {
    const int b = blockIdx.x;
    const int t = threadIdx.x;
    if (t < 128) {
        float acc = b_attn[t];
        const float4* hrow = (const float4*)(hidden + b * DD);
        const float4* wrow = (const float4*)(W_attn + t * FAN);
        #pragma unroll
        for (int e = 0; e < 32; e++) {
            float4 h = hrow[e], w = wrow[e];
            acc += h.x * w.x + h.y * w.y + h.z * w.z + h.w * w.w;
        }
        hproj[b * DD + t] = acc;
        if (b == 0) v_out[t] = v_w[t];
    } else {
        int tt = t - 128;
        int d  = 2 * b + (tt >> 6);
        int e0 = (tt & 63) * 2;          // even element index; writes pair (e0,e0+1)
        float2 src = *(const float2*)(W_attn + d * FAN + DD + e0);
        union { __hip_bfloat162 bb; unsigned u; } c;
        c.bb = __float22bfloat162_rn(src);
        unsigned off = (unsigned)(d * 256)
                     + (((unsigned)(e0 * 2)) ^ (((unsigned)d & 7u) << 4));
        *(unsigned*)(Wb + off) = c.u;
    }
}

// ---------------------------------------------------------------------------
// Kernel 2 (R4 base + deeper pipeline; occupancy UNCHANGED at 4 waves/SIMD —
// R6 lesson: this kernel is latency-bound, never trade occupancy):
// out[b][s] = exp(v . tanh(hproj[b] + X[s] @ We^T)) (0 if masked).
// Max-free exp safe: |logit| <= ||v||_1 <= 128/sqrt(128) = 11.31.
// - ALL 4 tiles' masks loaded up front: kills the per-tile serial chain
//   mask-load -> guarded A-load -> use.
// - A-prefetch distance 2 via 3-slot ring (static indices, unrolled loop):
//   load->use distance ~2 tiles (~1400 cyc) > worst-case HBM latency.
// grid (16, 64) x 256.
// ---------------------------------------------------------------------------
__global__ __launch_bounds__(256, 4) void logits_kernel(
        const float* __restrict__ seq_embs, const int* __restrict__ mask,
        const float* __restrict__ hproj, const unsigned char* __restrict__ Wb,
        const float* __restrict__ v, float* __restrict__ out,
        float* __restrict__ psums) {
    __shared__ __attribute__((aligned(1024))) unsigned char Ws[DD * EE * 2]; // 32 KB

    const int b    = blockIdx.y;
    const int g    = blockIdx.x;
    const int tid  = threadIdx.x;
    const int wave = tid >> 6;
    const int lane = tid & 63;
    const int m    = lane & 15;
    const int quad = lane >> 4;
    const int arow = wave * 16 + m;       // this lane's s-row within each tile

    // --- Stage swizzled We image via direct global->LDS DMA (identity copy).
    #pragma unroll
    for (int j = 0; j < 8; j++) {
        const int c = wave * 8 + j;
        __builtin_amdgcn_global_load_lds(
            (const __attribute__((address_space(1))) unsigned int*)(Wb + c * 1024 + lane * 16),
            (__attribute__((address_space(3))) unsigned int*)(Ws + c * 1024),
            16, 0, 0);
    }

    const int* __restrict__ mask_g = mask + (size_t)b * SS + g * ROWS;
    const float* __restrict__ xbase = seq_embs
        + (size_t)(g * ROWS + arow) * (BB * EE)
        + (size_t)b * EE + quad * 8;

    // --- ALL masks up front (removes mask->A dependency from the loop).
    int am[TILES];
    int4 mq[TILES];
    #pragma unroll
    for (int t = 0; t < TILES; t++) {
        am[t] = mask_g[t * 64 + arow];
        mq[t] = *(const int4*)(mask_g + t * 64 + wave * 16 + quad * 4);
    }

    // --- A-frag ring: 3 slots, prefetch distance 2.
    bf16x8 af[3][4];
    #define PREFETCH_A(T, SLOT)                                                \
    do {                                                                       \
        const float* xrow = xbase + (size_t)((T) * 64) * (BB * EE);            \
        _Pragma("unroll")                                                      \
        for (int kk = 0; kk < 4; kk++) {                                       \
            union { uint4 q; bf16x8 bf; } c;                                   \
            c.q = make_uint4(0u, 0u, 0u, 0u);                                  \
            if (am[(T)] != 0) {                                                \
                float4 f0 = *(const float4*)(xrow + kk * 32);                  \
                float4 f1 = *(const float4*)(xrow + kk * 32 + 4);              \
                uint2 a = f4_to_bf4(f0), bq = f4_to_bf4(f1);                   \
                c.q = make_uint4(a.x, a.y, bq.x, bq.y);                        \
            }                                                                  \
            af[(SLOT)][kk] = c.bf;                                             \
        }                                                                      \
    } while (0)

    PREFETCH_A(0, 0);
    PREFETCH_A(1, 1);

    // --- Per-lane epilogue constants (L2-hot).
    float hp_r[8], v_r[8];
    #pragma unroll
    for (int t = 0; t < 8; t++) {
        hp_r[t] = hproj[b * DD + t * 16 + m];
        v_r[t]  = v[t * 16 + m];
    }

    __syncthreads();   // drains vmcnt(0): staging DMA complete (Ws readable)

    const unsigned sw = ((unsigned)(m & 7)) << 4;   // read-side XOR (matches prep)
    float blocksum = 0.0f;

    #pragma unroll
    for (int tile = 0; tile < TILES; tile++) {
        const int cur = tile % 3;
        // Issue tile+2's A-loads now: ~2 tiles of compute cover the latency.
        if (tile + 2 < TILES) {
            PREFETCH_A(tile + 2, (tile + 2) % 3);
        }

        // --- MFMA: 64 s-rows x 128 d, K=128. 8 independent acc chains.
        f32x4 acc[8];
        #pragma unroll
        for (int t = 0; t < 8; t++) acc[t] = (f32x4){0.f, 0.f, 0.f, 0.f};
        #pragma unroll
        for (int kk = 0; kk < 4; kk++) {
            const unsigned cb = ((unsigned)(kk * 64 + quad * 16)) ^ sw;
            #pragma unroll
            for (int t = 0; t < 8; t++) {
                bf16x8 bf = ld_frag_lds(Ws + (unsigned)((t * 16 + m) * 256) + cb);
                acc[t] = __builtin_amdgcn_mfma_f32_16x16x32_bf16(af[cur][kk], bf, acc[t], 0, 0, 0);
            }
        }

        // --- Deferred epilogue: logit -> exp, mask-guarded (skip ~50% rows).
        const int mqa[4] = {mq[tile].x, mq[tile].y, mq[tile].z, mq[tile].w};
        float red[4];
        #pragma unroll
        for (int r = 0; r < 4; r++) {
            float red_r = 0.0f;
            if (mqa[r] != 0) {   // uniform across the 16-lane m-group: shfl-safe
                float part = 0.f;
                #pragma unroll
                for (int t = 0; t < 8; t++)
                    part += v_r[t] * tanh_fast(hp_r[t] + acc[t][r]);
                part += __shfl_xor(part, 1);
                part += __shfl_xor(part, 2);
                part += __shfl_xor(part, 4);
                part += __shfl_xor(part, 8);
                red_r = __expf(part);
            }
            red[r] = red_r;
            blocksum += red_r;
        }
        if (m == 0) {
            *(float4*)&out[(size_t)b * SS + g * ROWS + tile * 64
                           + wave * 16 + quad * 4] =
                make_float4(red[0], red[1], red[2], red[3]);
        }
    }
    #undef PREFETCH_A

    // One plain store per wave (no atomics, no hot-line contention).
    blocksum += __shfl_xor(blocksum, 16);
    blocksum += __shfl_xor(blocksum, 32);
    if (lane == 0) psums[(b * 16 + g) * 4 + wave] = blocksum;
}

// ---------------------------------------------------------------------------
// Kernel 3: reduce the 64 per-wave partials of row b, then out[b][s] *= inv.
// grid (4, 64) x 256.
// ---------------------------------------------------------------------------
__global__ __launch_bounds__(256) void norm_kernel(
        float* __restrict__ out, const float* __restrict__ psums) {
    const int b = blockIdx.y;
    const int tid = threadIdx.x;
    const int lane = tid & 63;
    float p = psums[b * 64 + lane];          // 64 partials, L2-hot
    #pragma unroll
    for (int off = 32; off >= 1; off >>= 1)
        p += __shfl_xor(p, off);
    const float inv = 1.0f / p;              // all lanes hold the full row sum
    const int i = (blockIdx.x * 256 + tid) * 4;
    float4 v = *(float4*)&out[(size_t)b * SS + i];
    v.x *= inv; v.y *= inv; v.z *= inv; v.w *= inv;
    *(float4*)&out[(size_t)b * SS + i] = v;
}

extern "C" void kernel_launch(void* const* d_in, const int* in_sizes, int n_in,
                              void* d_out, int out_size, void* d_ws, size_t ws_size,
                              hipStream_t stream) {
    const float* hidden   = (const float*)d_in[0];
    const float* seq_embs = (const float*)d_in[1];
    const int*   mask     = (const int*)d_in[2];
    const float* W_attn   = (const float*)d_in[3];
    const float* b_attn   = (const float*)d_in[4];
    const float* v_w      = (const float*)d_in[5];
    float* out = (float*)d_out;

    float*         hproj = (float*)d_ws;                            // 32 KB
    unsigned char* Wb    = (unsigned char*)d_ws + 32768;            // 32 KB swizzled image
    float*         vv    = (float*)((char*)d_ws + 65536);           // 512 B
    float*         psums = (float*)((char*)d_ws + 66048);           // 16 KB (64 x 64)

    prep_kernel<<<64, 256, 0, stream>>>(hidden, W_attn, b_attn, v_w, hproj, Wb, vv);
    dim3 grid(SS / ROWS, BB);          // (16, 64)
    logits_kernel<<<grid, 256, 0, stream>>>(seq_embs, mask, hproj, Wb, vv, out, psums);
    dim3 ngrid(SS / (256 * 4), BB);    // (4, 64)
    norm_kernel<<<ngrid, 256, 0, stream>>>(out, psums);
}